// Round 1
// baseline (102.553 us; speedup 1.0000x reference)
//
#include <hip/hip_runtime.h>

#define NPTS 1024
#define D 64

__device__ __forceinline__ float fast_silu(float h) {
    // silu(h) = h / (1 + exp(-h)); v_exp + v_rcp, ~1ulp each, fine vs 0.137 absmax budget
    float e = __expf(-h);
    return h * __builtin_amdgcn_rcpf(1.0f + e);
}

// Kernel A: hi = x@W1_i + b1, hj = x@W1_j, wib = x@Wc_i + bc, wj = x@Wc_j
__global__ __launch_bounds__(256) void precomp_kernel(
    const float* __restrict__ x, const float* __restrict__ W1,
    const float* __restrict__ b1, const float* __restrict__ Wc,
    const float* __restrict__ bc,
    float* __restrict__ hib, float* __restrict__ hj,
    float* __restrict__ wib, float* __restrict__ wj)
{
    __shared__ float xs[4][D];
    const int t = threadIdx.x;
    const int r = t >> 6, c = t & 63;
    const int row = blockIdx.x * 4 + r;
    xs[r][c] = x[row * D + c];
    __syncthreads();
    float ai = 0.f, aj = 0.f;
    #pragma unroll 8
    for (int k = 0; k < D; ++k) {
        const float xv = xs[r][k];
        ai = fmaf(xv, W1[k * D + c], ai);          // W1_i column c
        aj = fmaf(xv, W1[(D + k) * D + c], aj);    // W1_j column c
    }
    hib[row * D + c] = ai + b1[c];
    hj[row * D + c]  = aj;
    // Wc dots: wave reduction over the 64 channels
    float pi = xs[r][c] * Wc[c];
    float pj = xs[r][c] * Wc[D + c];
    #pragma unroll
    for (int off = 32; off; off >>= 1) {
        pi += __shfl_down(pi, off, 64);
        pj += __shfl_down(pj, off, 64);
    }
    if (c == 0) { wib[row] = pi + bc[0]; wj[row] = pj; }
}

// Kernel B: per block = 2 rows i. Phase1: dists + coord gate. Phase2: S[i,c] accumulation.
// Phase3: S @ W2 + b2, coords output.
__global__ __launch_bounds__(256) void pair_kernel(
    const float* __restrict__ coords,
    const float* __restrict__ W1, const float* __restrict__ W2,
    const float* __restrict__ b2, const float* __restrict__ Wc,
    const float* __restrict__ hib_g, const float* __restrict__ hj_g,
    const float* __restrict__ wib_g, const float* __restrict__ wj_g,
    float* __restrict__ out)
{
    __shared__ float cs[NPTS * 3];      // 12 KB: all coords
    __shared__ float wjs[NPTS];         // 4 KB
    __shared__ float dist_s[2][NPTS];   // 8 KB
    __shared__ float S4[4][2][D];       // 2 KB: per-wave partial S
    __shared__ float dred[4][2][3];     // coord partials per wave

    const int t = threadIdx.x;
    const int i0 = blockIdx.x * 2;

    for (int k = t; k < NPTS * 3; k += 256) cs[k] = coords[k];
    for (int k = t; k < NPTS; k += 256) wjs[k] = wj_g[k];
    __syncthreads();

    const float wcd = Wc[2 * D];
    float dcx[2] = {0.f, 0.f}, dcy[2] = {0.f, 0.f}, dcz[2] = {0.f, 0.f};

    // ---- Phase 1: dist + silu-gated coordinate update (1M pairs total over grid)
    #pragma unroll
    for (int is = 0; is < 2; ++is) {
        const int i = i0 + is;
        const float cix = cs[i*3+0], ciy = cs[i*3+1], ciz = cs[i*3+2];
        const float wib = wib_g[i];
        #pragma unroll
        for (int it = 0; it < 4; ++it) {
            const int j = it * 256 + t;
            const float rx = cix - cs[j*3+0];
            const float ry = ciy - cs[j*3+1];
            const float rz = ciz - cs[j*3+2];
            const float d = sqrtf(fmaf(rx, rx, fmaf(ry, ry, rz * rz)));
            dist_s[is][j] = d;
            const float wv = fmaf(d, wcd, wib + wjs[j]);
            const float sw = fast_silu(wv);
            dcx[is] = fmaf(sw, rx, dcx[is]);
            dcy[is] = fmaf(sw, ry, dcy[is]);
            dcz[is] = fmaf(sw, rz, dcz[is]);
        }
    }
    __syncthreads();  // dist_s ready

    // ---- Phase 2: S[i,c] = sum_j silu(hi + hj + d*w1d). Wave w owns a 256-j quarter,
    // hj value reused for both i's in registers (halves L2 traffic).
    const int w = t >> 6, c = t & 63;
    const float hib0 = hib_g[i0 * D + c];
    const float hib1 = hib_g[(i0 + 1) * D + c];
    const float w1dc = W1[2 * D * D + c];
    float acc0 = 0.f, acc1 = 0.f;
    const float* __restrict__ hp  = hj_g + (w * 256) * D + c;
    const float* __restrict__ dp0 = &dist_s[0][w * 256];
    const float* __restrict__ dp1 = &dist_s[1][w * 256];
    #pragma unroll 4
    for (int jj = 0; jj < 256; ++jj) {
        const float hv = hp[jj * D];        // coalesced, L1/L2-hot
        const float d0 = dp0[jj];           // LDS broadcast
        const float d1 = dp1[jj];
        const float h0 = fmaf(d0, w1dc, hib0) + hv;
        const float h1 = fmaf(d1, w1dc, hib1) + hv;
        acc0 += fast_silu(h0);
        acc1 += fast_silu(h1);
    }
    S4[w][0][c] = acc0;
    S4[w][1][c] = acc1;

    // wave-reduce coordinate partials
    #pragma unroll
    for (int is = 0; is < 2; ++is) {
        float vx = dcx[is], vy = dcy[is], vz = dcz[is];
        #pragma unroll
        for (int off = 32; off; off >>= 1) {
            vx += __shfl_down(vx, off, 64);
            vy += __shfl_down(vy, off, 64);
            vz += __shfl_down(vz, off, 64);
        }
        if (c == 0) { dred[w][is][0] = vx; dred[w][is][1] = vy; dred[w][is][2] = vz; }
    }
    __syncthreads();

    // ---- Phase 3: msg_x[i] = (S/N) @ W2 + b2
    if (t < 128) {
        const int is = t >> 6, cp = t & 63;
        float acc = 0.f;
        #pragma unroll 8
        for (int cc = 0; cc < D; ++cc) {
            const float S = S4[0][is][cc] + S4[1][is][cc] + S4[2][is][cc] + S4[3][is][cc];
            acc = fmaf(S, W2[cc * D + cp], acc);
        }
        out[(i0 + is) * D + cp] = fmaf(acc, 1.0f / 1024.0f, b2[cp]);
    }
    if (t < 6) {
        const int is = t / 3, comp = t - is * 3;
        const float tot = dred[0][is][comp] + dred[1][is][comp]
                        + dred[2][is][comp] + dred[3][is][comp];
        out[NPTS * D + (i0 + is) * 3 + comp] =
            cs[(i0 + is) * 3 + comp] + tot * (1.0f / 1024.0f);
    }
}

extern "C" void kernel_launch(void* const* d_in, const int* in_sizes, int n_in,
                              void* d_out, int out_size, void* d_ws, size_t ws_size,
                              hipStream_t stream)
{
    const float* x      = (const float*)d_in[0];
    const float* coords = (const float*)d_in[1];
    const float* W1     = (const float*)d_in[2];
    const float* b1     = (const float*)d_in[3];
    const float* W2     = (const float*)d_in[4];
    const float* b2     = (const float*)d_in[5];
    const float* Wc     = (const float*)d_in[6];
    const float* bc     = (const float*)d_in[7];
    float* out = (float*)d_out;

    float* hib = (float*)d_ws;        // 1024*64
    float* hj  = hib + NPTS * D;      // 1024*64
    float* wib = hj + NPTS * D;       // 1024
    float* wj  = wib + NPTS;          // 1024

    precomp_kernel<<<NPTS / 4, 256, 0, stream>>>(x, W1, b1, Wc, bc, hib, hj, wib, wj);
    pair_kernel<<<NPTS / 2, 256, 0, stream>>>(coords, W1, W2, b2, Wc,
                                              hib, hj, wib, wj, out);
}

// Round 2
// 95.603 us; speedup vs baseline: 1.0727x; 1.0727x over previous
//
#include <hip/hip_runtime.h>

#define NPTS 1024
#define D 64

__device__ __forceinline__ float fast_silu(float h) {
    // silu(h) = h / (1 + exp(-h)); v_exp + v_rcp; absmax budget 0.137 >> ~1e-4 error
    float e = __expf(-h);
    return h * __builtin_amdgcn_rcpf(1.0f + e);
}

// Kernel A: hib = x@W1_i + b1, hj = x@W1_j, wib = x@Wc_i + bc, wj = x@Wc_j
__global__ __launch_bounds__(256) void precomp_kernel(
    const float* __restrict__ x, const float* __restrict__ W1,
    const float* __restrict__ b1, const float* __restrict__ Wc,
    const float* __restrict__ bc,
    float* __restrict__ hib, float* __restrict__ hj,
    float* __restrict__ wib, float* __restrict__ wj)
{
    __shared__ float xs[4][D];
    const int t = threadIdx.x;
    const int r = t >> 6, c = t & 63;
    const int row = blockIdx.x * 4 + r;
    xs[r][c] = x[row * D + c];
    __syncthreads();
    float ai = 0.f, aj = 0.f;
    #pragma unroll 8
    for (int k = 0; k < D; ++k) {
        const float xv = xs[r][k];
        ai = fmaf(xv, W1[k * D + c], ai);          // W1_i column c
        aj = fmaf(xv, W1[(D + k) * D + c], aj);    // W1_j column c
    }
    hib[row * D + c] = ai + b1[c];
    hj[row * D + c]  = aj;
    // Wc dots: wave reduction over the 64 channels
    float pi = xs[r][c] * Wc[c];
    float pj = xs[r][c] * Wc[D + c];
    #pragma unroll
    for (int off = 32; off; off >>= 1) {
        pi += __shfl_down(pi, off, 64);
        pj += __shfl_down(pj, off, 64);
    }
    if (c == 0) { wib[row] = pi + bc[0]; wj[row] = pj; }
}

// Kernel B: per block = 2 rows i.
// Phase 1: dists + silu-gated coordinate update.
// Phase 2: S[i,c] = sum_j silu(hi + hj + d*W1d)  — float4 lanes-x-channels layout.
// Phase 3: msg_x = (S/N)@W2 + b2; coords_new.
__global__ __launch_bounds__(256) void pair_kernel(
    const float* __restrict__ coords,
    const float* __restrict__ W1, const float* __restrict__ W2,
    const float* __restrict__ b2, const float* __restrict__ Wc,
    const float* __restrict__ hib_g, const float* __restrict__ hj_g,
    const float* __restrict__ wib_g, const float* __restrict__ wj_g,
    float* __restrict__ out)
{
    __shared__ float cs[NPTS * 3];      // 12 KB: all coords
    __shared__ float wjs[NPTS];         // 4 KB
    __shared__ float dist_s[2][NPTS];   // 8 KB
    __shared__ float S4[4][2][D];       // 2 KB: per-wave partial S
    __shared__ float dred[4][2][3];     // coord partials per wave

    const int t = threadIdx.x;
    const int i0 = blockIdx.x * 2;

    for (int k = t; k < NPTS * 3; k += 256) cs[k] = coords[k];
    for (int k = t; k < NPTS; k += 256) wjs[k] = wj_g[k];
    __syncthreads();

    const float wcd = Wc[2 * D];
    float dcx[2] = {0.f, 0.f}, dcy[2] = {0.f, 0.f}, dcz[2] = {0.f, 0.f};

    // ---- Phase 1: dist + silu-gated coordinate update
    #pragma unroll
    for (int is = 0; is < 2; ++is) {
        const int i = i0 + is;
        const float cix = cs[i*3+0], ciy = cs[i*3+1], ciz = cs[i*3+2];
        const float wib = wib_g[i];
        #pragma unroll
        for (int it = 0; it < 4; ++it) {
            const int j = it * 256 + t;
            const float rx = cix - cs[j*3+0];
            const float ry = ciy - cs[j*3+1];
            const float rz = ciz - cs[j*3+2];
            const float d = sqrtf(fmaf(rx, rx, fmaf(ry, ry, rz * rz)));
            dist_s[is][j] = d;
            const float wv = fmaf(d, wcd, wib + wjs[j]);
            const float sw = fast_silu(wv);
            dcx[is] = fmaf(sw, rx, dcx[is]);
            dcy[is] = fmaf(sw, ry, dcy[is]);
            dcz[is] = fmaf(sw, rz, dcz[is]);
        }
    }

    // wave-reduce coordinate partials (do it here, overlaps with barrier)
    {
        const int w = t >> 6, l = t & 63;
        #pragma unroll
        for (int is = 0; is < 2; ++is) {
            float vx = dcx[is], vy = dcy[is], vz = dcz[is];
            #pragma unroll
            for (int off = 32; off; off >>= 1) {
                vx += __shfl_down(vx, off, 64);
                vy += __shfl_down(vy, off, 64);
                vz += __shfl_down(vz, off, 64);
            }
            if (l == 0) { dred[w][is][0] = vx; dred[w][is][1] = vy; dred[w][is][2] = vz; }
        }
    }
    __syncthreads();  // dist_s ready

    // ---- Phase 2: 16 lanes (channel quads) x 4 j-subslots per wave.
    // Wave w owns j in [w*256, w*256+256); thread handles 4 channels x 2 rows.
    const int w = t >> 6, l = t & 63;
    const int sub = l >> 4;          // j sub-slot 0..3
    const int q   = l & 15;          // channel quad: channels q*4 .. q*4+3
    const float4 hib0 = *(const float4*)&hib_g[ i0      * D + q * 4];
    const float4 hib1 = *(const float4*)&hib_g[(i0 + 1) * D + q * 4];
    const float4 w1d4 = *(const float4*)&W1[2 * D * D + q * 4];
    float4 acc0 = {0.f, 0.f, 0.f, 0.f};
    float4 acc1 = {0.f, 0.f, 0.f, 0.f};
    const int jbase = w * 256 + sub;
    const float* __restrict__ hjp = hj_g + (size_t)jbase * D + q * 4;
    #pragma unroll 4
    for (int it = 0; it < 64; ++it) {
        const int j = jbase + it * 4;
        const float4 hv = *(const float4*)(hjp + (size_t)it * 4 * D);  // dwordx4, coalesced
        const float d0 = dist_s[0][j];
        const float d1 = dist_s[1][j];
        acc0.x += fast_silu(fmaf(d0, w1d4.x, hib0.x) + hv.x);
        acc0.y += fast_silu(fmaf(d0, w1d4.y, hib0.y) + hv.y);
        acc0.z += fast_silu(fmaf(d0, w1d4.z, hib0.z) + hv.z);
        acc0.w += fast_silu(fmaf(d0, w1d4.w, hib0.w) + hv.w);
        acc1.x += fast_silu(fmaf(d1, w1d4.x, hib1.x) + hv.x);
        acc1.y += fast_silu(fmaf(d1, w1d4.y, hib1.y) + hv.y);
        acc1.z += fast_silu(fmaf(d1, w1d4.z, hib1.z) + hv.z);
        acc1.w += fast_silu(fmaf(d1, w1d4.w, hib1.w) + hv.w);
    }
    // reduce the 4 j-subslot partials (lanes differing in bits 4..5, same q)
    #pragma unroll
    for (int off = 16; off <= 32; off <<= 1) {
        acc0.x += __shfl_xor(acc0.x, off, 64);
        acc0.y += __shfl_xor(acc0.y, off, 64);
        acc0.z += __shfl_xor(acc0.z, off, 64);
        acc0.w += __shfl_xor(acc0.w, off, 64);
        acc1.x += __shfl_xor(acc1.x, off, 64);
        acc1.y += __shfl_xor(acc1.y, off, 64);
        acc1.z += __shfl_xor(acc1.z, off, 64);
        acc1.w += __shfl_xor(acc1.w, off, 64);
    }
    if (sub == 0) {
        *(float4*)&S4[w][0][q * 4] = acc0;
        *(float4*)&S4[w][1][q * 4] = acc1;
    }
    __syncthreads();

    // ---- Phase 3: msg_x[i] = (S/N) @ W2 + b2
    if (t < 128) {
        const int is = t >> 6, cp = t & 63;
        float acc = 0.f;
        #pragma unroll 8
        for (int cc = 0; cc < D; ++cc) {
            const float S = S4[0][is][cc] + S4[1][is][cc] + S4[2][is][cc] + S4[3][is][cc];
            acc = fmaf(S, W2[cc * D + cp], acc);
        }
        out[(i0 + is) * D + cp] = fmaf(acc, 1.0f / 1024.0f, b2[cp]);
    }
    if (t < 6) {
        const int is = t / 3, comp = t - is * 3;
        const float tot = dred[0][is][comp] + dred[1][is][comp]
                        + dred[2][is][comp] + dred[3][is][comp];
        out[NPTS * D + (i0 + is) * 3 + comp] =
            cs[(i0 + is) * 3 + comp] + tot * (1.0f / 1024.0f);
    }
}

extern "C" void kernel_launch(void* const* d_in, const int* in_sizes, int n_in,
                              void* d_out, int out_size, void* d_ws, size_t ws_size,
                              hipStream_t stream)
{
    const float* x      = (const float*)d_in[0];
    const float* coords = (const float*)d_in[1];
    const float* W1     = (const float*)d_in[2];
    const float* b1     = (const float*)d_in[3];
    const float* W2     = (const float*)d_in[4];
    const float* b2     = (const float*)d_in[5];
    const float* Wc     = (const float*)d_in[6];
    const float* bc     = (const float*)d_in[7];
    float* out = (float*)d_out;

    float* hib = (float*)d_ws;        // 1024*64
    float* hj  = hib + NPTS * D;      // 1024*64
    float* wib = hj + NPTS * D;       // 1024
    float* wj  = wib + NPTS;          // 1024

    precomp_kernel<<<NPTS / 4, 256, 0, stream>>>(x, W1, b1, Wc, bc, hib, hj, wib, wj);
    pair_kernel<<<NPTS / 2, 256, 0, stream>>>(coords, W1, W2, b2, Wc,
                                              hib, hj, wib, wj, out);
}

// Round 3
// 92.660 us; speedup vs baseline: 1.1068x; 1.0318x over previous
//
#include <hip/hip_runtime.h>

#define NPTS 1024
#define D 64

#define LOG2E 1.44269504088896f
#define LN2C  0.69314718055995f

__device__ __forceinline__ float exp2_fast(float x) {
#if __has_builtin(__builtin_amdgcn_exp2f)
    return __builtin_amdgcn_exp2f(x);   // v_exp_f32
#else
    return exp2f(x);
#endif
}
__device__ __forceinline__ float sqrt_fast(float x) {
#if __has_builtin(__builtin_amdgcn_sqrtf)
    return __builtin_amdgcn_sqrtf(x);
#else
    return sqrtf(x);
#endif
}

// Kernel A: hib = (x@W1_i + b1)*log2e, hj = (x@W1_j)*log2e,
//           wib = (x@Wc_i + bc)*log2e, wj = (x@Wc_j)*log2e
__global__ __launch_bounds__(256) void precomp_kernel(
    const float* __restrict__ x, const float* __restrict__ W1,
    const float* __restrict__ b1, const float* __restrict__ Wc,
    const float* __restrict__ bc,
    float* __restrict__ hib, float* __restrict__ hj,
    float* __restrict__ wib, float* __restrict__ wj)
{
    __shared__ float xs[4][D];
    const int t = threadIdx.x;
    const int r = t >> 6, c = t & 63;
    const int row = blockIdx.x * 4 + r;
    xs[r][c] = x[row * D + c];
    __syncthreads();
    float ai = 0.f, aj = 0.f;
    #pragma unroll 8
    for (int k = 0; k < D; ++k) {
        const float xv = xs[r][k];
        ai = fmaf(xv, W1[k * D + c], ai);          // W1_i column c
        aj = fmaf(xv, W1[(D + k) * D + c], aj);    // W1_j column c
    }
    hib[row * D + c] = (ai + b1[c]) * LOG2E;
    hj[row * D + c]  = aj * LOG2E;
    // Wc dots: wave reduction over the 64 channels
    float pi = xs[r][c] * Wc[c];
    float pj = xs[r][c] * Wc[D + c];
    #pragma unroll
    for (int off = 32; off; off >>= 1) {
        pi += __shfl_down(pi, off, 64);
        pj += __shfl_down(pj, off, 64);
    }
    if (c == 0) { wib[row] = (pi + bc[0]) * LOG2E; wj[row] = pj * LOG2E; }
}

// Kernel B: per block = 2 rows i. All silu arguments arrive pre-scaled by
// log2e, so exp(-h) = v_exp_f32(-t) with free neg modifier; the compensating
// *ln2 is folded into the (1/1024) epilogue constants.
__global__ __launch_bounds__(256) void pair_kernel(
    const float* __restrict__ coords,
    const float* __restrict__ W1, const float* __restrict__ W2,
    const float* __restrict__ b2, const float* __restrict__ Wc,
    const float* __restrict__ hib_g, const float* __restrict__ hj_g,
    const float* __restrict__ wib_g, const float* __restrict__ wj_g,
    float* __restrict__ out)
{
    __shared__ float cs[NPTS * 3];      // 12 KB: all coords
    __shared__ float wjs[NPTS];         // 4 KB (pre-scaled)
    __shared__ float dist_s[2][NPTS];   // 8 KB (UNscaled dists)
    __shared__ float S4[4][2][D];       // 2 KB: per-wave partial S (scaled)
    __shared__ float S2[2][D];          // wave-reduced S
    __shared__ float dred[4][2][3];     // coord partials per wave

    const int t = threadIdx.x;
    const int i0 = blockIdx.x * 2;

    for (int k = t; k < NPTS * 3; k += 256) cs[k] = coords[k];
    for (int k = t; k < NPTS; k += 256) wjs[k] = wj_g[k];
    __syncthreads();

    const float wcd = Wc[2 * D] * LOG2E;
    float dcx[2] = {0.f, 0.f}, dcy[2] = {0.f, 0.f}, dcz[2] = {0.f, 0.f};

    // ---- Phase 1: dist + silu-gated coordinate update
    #pragma unroll
    for (int is = 0; is < 2; ++is) {
        const int i = i0 + is;
        const float cix = cs[i*3+0], ciy = cs[i*3+1], ciz = cs[i*3+2];
        const float wib = wib_g[i];           // pre-scaled
        #pragma unroll
        for (int it = 0; it < 4; ++it) {
            const int j = it * 256 + t;
            const float rx = cix - cs[j*3+0];
            const float ry = ciy - cs[j*3+1];
            const float rz = ciz - cs[j*3+2];
            const float d = sqrt_fast(fmaf(rx, rx, fmaf(ry, ry, rz * rz)));
            dist_s[is][j] = d;
            const float tv = fmaf(d, wcd, wib + wjs[j]);   // log2e * w
            const float e  = exp2_fast(-tv);               // e^{-w}
            const float sw = tv * __builtin_amdgcn_rcpf(1.0f + e); // log2e*silu(w)
            dcx[is] = fmaf(sw, rx, dcx[is]);
            dcy[is] = fmaf(sw, ry, dcy[is]);
            dcz[is] = fmaf(sw, rz, dcz[is]);
        }
    }

    // wave-reduce coordinate partials
    {
        const int w = t >> 6, l = t & 63;
        #pragma unroll
        for (int is = 0; is < 2; ++is) {
            float vx = dcx[is], vy = dcy[is], vz = dcz[is];
            #pragma unroll
            for (int off = 32; off; off >>= 1) {
                vx += __shfl_down(vx, off, 64);
                vy += __shfl_down(vy, off, 64);
                vz += __shfl_down(vz, off, 64);
            }
            if (l == 0) { dred[w][is][0] = vx; dred[w][is][1] = vy; dred[w][is][2] = vz; }
        }
    }
    __syncthreads();  // dist_s ready

    // ---- Phase 2: 16 lanes (channel quads) x 4 j-subslots per wave.
    const int w = t >> 6, l = t & 63;
    const int sub = l >> 4;          // j sub-slot 0..3
    const int q   = l & 15;          // channel quad
    const float4 hib0 = *(const float4*)&hib_g[ i0      * D + q * 4];
    const float4 hib1 = *(const float4*)&hib_g[(i0 + 1) * D + q * 4];
    float4 w1d4 = *(const float4*)&W1[2 * D * D + q * 4];
    w1d4.x *= LOG2E; w1d4.y *= LOG2E; w1d4.z *= LOG2E; w1d4.w *= LOG2E;
    float4 acc0 = {0.f, 0.f, 0.f, 0.f};
    float4 acc1 = {0.f, 0.f, 0.f, 0.f};
    const int jbase = w * 256 + sub;
    const float* __restrict__ hjp = hj_g + (size_t)jbase * D + q * 4;

    #define SILU_ACC(accv, tv)                                               \
        { const float e_ = exp2_fast(-(tv));                                 \
          accv = fmaf((tv), __builtin_amdgcn_rcpf(1.0f + e_), accv); }

    #pragma unroll 4
    for (int it = 0; it < 64; ++it) {
        const int j = jbase + it * 4;
        const float4 hv = *(const float4*)(hjp + (size_t)it * 4 * D);  // dwordx4
        const float d0 = dist_s[0][j];
        const float d1 = dist_s[1][j];
        const float t0x = fmaf(d0, w1d4.x, hib0.x) + hv.x;
        const float t0y = fmaf(d0, w1d4.y, hib0.y) + hv.y;
        const float t0z = fmaf(d0, w1d4.z, hib0.z) + hv.z;
        const float t0w = fmaf(d0, w1d4.w, hib0.w) + hv.w;
        const float t1x = fmaf(d1, w1d4.x, hib1.x) + hv.x;
        const float t1y = fmaf(d1, w1d4.y, hib1.y) + hv.y;
        const float t1z = fmaf(d1, w1d4.z, hib1.z) + hv.z;
        const float t1w = fmaf(d1, w1d4.w, hib1.w) + hv.w;
        SILU_ACC(acc0.x, t0x); SILU_ACC(acc0.y, t0y);
        SILU_ACC(acc0.z, t0z); SILU_ACC(acc0.w, t0w);
        SILU_ACC(acc1.x, t1x); SILU_ACC(acc1.y, t1y);
        SILU_ACC(acc1.z, t1z); SILU_ACC(acc1.w, t1w);
    }
    // reduce the 4 j-subslot partials
    #pragma unroll
    for (int off = 16; off <= 32; off <<= 1) {
        acc0.x += __shfl_xor(acc0.x, off, 64);
        acc0.y += __shfl_xor(acc0.y, off, 64);
        acc0.z += __shfl_xor(acc0.z, off, 64);
        acc0.w += __shfl_xor(acc0.w, off, 64);
        acc1.x += __shfl_xor(acc1.x, off, 64);
        acc1.y += __shfl_xor(acc1.y, off, 64);
        acc1.z += __shfl_xor(acc1.z, off, 64);
        acc1.w += __shfl_xor(acc1.w, off, 64);
    }
    if (sub == 0) {
        *(float4*)&S4[w][0][q * 4] = acc0;
        *(float4*)&S4[w][1][q * 4] = acc1;
    }
    __syncthreads();

    // ---- Phase 3a: reduce S4 across waves
    if (t < 128) {
        const int is = t >> 6, cc = t & 63;
        S2[is][cc] = S4[0][is][cc] + S4[1][is][cc] + S4[2][is][cc] + S4[3][is][cc];
    }
    __syncthreads();

    // ---- Phase 3b: msg_x[i] = (S*ln2/N) @ W2 + b2 ; coords output
    if (t < 128) {
        const int is = t >> 6, cp = t & 63;
        float acc = 0.f;
        #pragma unroll 16
        for (int cc = 0; cc < D; ++cc)
            acc = fmaf(S2[is][cc], W2[cc * D + cp], acc);
        out[(i0 + is) * D + cp] = fmaf(acc, LN2C / 1024.0f, b2[cp]);
    }
    if (t < 6) {
        const int is = t / 3, comp = t - is * 3;
        const float tot = dred[0][is][comp] + dred[1][is][comp]
                        + dred[2][is][comp] + dred[3][is][comp];
        out[NPTS * D + (i0 + is) * 3 + comp] =
            cs[(i0 + is) * 3 + comp] + tot * (LN2C / 1024.0f);
    }
}

extern "C" void kernel_launch(void* const* d_in, const int* in_sizes, int n_in,
                              void* d_out, int out_size, void* d_ws, size_t ws_size,
                              hipStream_t stream)
{
    const float* x      = (const float*)d_in[0];
    const float* coords = (const float*)d_in[1];
    const float* W1     = (const float*)d_in[2];
    const float* b1     = (const float*)d_in[3];
    const float* W2     = (const float*)d_in[4];
    const float* b2     = (const float*)d_in[5];
    const float* Wc     = (const float*)d_in[6];
    const float* bc     = (const float*)d_in[7];
    float* out = (float*)d_out;

    float* hib = (float*)d_ws;        // 1024*64
    float* hj  = hib + NPTS * D;      // 1024*64
    float* wib = hj + NPTS * D;       // 1024
    float* wj  = wib + NPTS;          // 1024

    precomp_kernel<<<NPTS / 4, 256, 0, stream>>>(x, W1, b1, Wc, bc, hib, hj, wib, wj);
    pair_kernel<<<NPTS / 2, 256, 0, stream>>>(coords, W1, W2, b2, Wc,
                                              hib, hj, wib, wj, out);
}